// Round 4
// baseline (354.175 us; speedup 1.0000x reference)
//
#include <hip/hip_runtime.h>

// Deformable depthwise 3x3 conv, B=8 C=256 H=W=96, fp32.
// R3 post-mortem: LDS gather was bank-conflict-bound (38.7M conflict cycles,
// ~35% of kernel) because bank=(4*yc+xc)%32 mixed per-lane row jitter into
// the bank index; plus 18 ds_read2_b32 per channel.
// R4: duplicated row-pair layout lp[y][x]={x[y][x],x[y+1][x]}, pair stride 96
// float2 (=192 dwords = 0 mod 32) -> bank depends on xc only (near-consecutive
// across lanes). All 4 bilinear corners live in two adjacent 8B slots -> one
// ds_read2_b64 per tap (9 LDS instr/channel). Staging: 2 coalesced 8B global
// loads -> 1 bank-cycled ds_write_b128 per 16B chunk.

constexpr int B_ = 8, C_ = 256, H_ = 96, W_ = 96;
constexpr int HW_ = H_ * W_;
constexpr int TH = 4;              // pixel rows per block
constexpr int NT = TH * W_;        // 384 threads = 6 waves
constexpr int CSPLIT = 8;
constexpr int CPB = C_ / CSPLIT;   // 32 channels per block
constexpr int MAXR = 48;           // max staged pair-rows: 48*96*8B = 36864 B
constexpr int CPR = W_ / 2;        // 16B chunks per pair-row = 48

__global__ __launch_bounds__(NT) void deform_dw_conv(
    const float* __restrict__ x, const float* __restrict__ off,
    const float* __restrict__ wgt, const float* __restrict__ bias,
    float* __restrict__ out)
{
    __shared__ float2 lp[MAXR * W_];
    __shared__ int s_rmin, s_rmax;

    const int tid  = threadIdx.x;
    const int r    = tid / W_;
    const int wcol = tid - r * W_;
    const int h    = blockIdx.x * TH + r;
    const int b    = blockIdx.y;
    const int c0   = blockIdx.z * CPB;

    if (tid == 0) { s_rmin = H_; s_rmax = -1; }
    __syncthreads();

    const float* offp = off + (size_t)b * 18 * HW_ + (size_t)h * W_ + wcol;

    // Per-(pixel,tap) params: weights pre-permuted onto loaded positions
    // [0]=(yc,xc) [1]=(yc,xc+1) [2]=(yc+1,xc) [3]=(yc+1,xc+1); validity folded
    // into weights (invalid corners weight 0).
    float cw[9][4];
    int yci[9], xci[9];
    int myrmin = H_, myrmax = -1;

#pragma unroll
    for (int kk = 0; kk < 9; ++kk) {
        const int i = kk / 3, j = kk % 3;
        const float py = (float)(h - 1 + i) + offp[(2 * kk) * HW_];
        const float px = (float)(wcol - 1 + j) + offp[(2 * kk + 1) * HW_];
        const float fy = floorf(py), fx = floorf(px);
        const float wy = py - fy, wx = px - fx;
        const int y0 = (int)fy, x0 = (int)fx;
        const bool vy0 = (unsigned)y0 < (unsigned)H_;
        const bool vy1 = (unsigned)(y0 + 1) < (unsigned)H_;
        const bool vx0 = (unsigned)x0 < (unsigned)W_;
        const bool vx1 = (unsigned)(x0 + 1) < (unsigned)W_;
        const float w00 = (vy0 && vx0) ? (1.f - wy) * (1.f - wx) : 0.f;
        const float w01 = (vy0 && vx1) ? (1.f - wy) * wx : 0.f;
        const float w10 = (vy1 && vx0) ? wy * (1.f - wx) : 0.f;
        const float w11 = (vy1 && vx1) ? wy * wx : 0.f;
        const int yc = min(max(y0, 0), H_ - 2);
        const int xc = min(max(x0, 0), W_ - 2);
        const bool rs = (y0 == yc);
        const bool cs = (x0 == xc);
        cw[kk][0] = rs ? (cs ? w00 : w01) : (cs ? w10 : w11);
        cw[kk][1] = rs ? (cs ? w01 : w00) : (cs ? w11 : w10);
        cw[kk][2] = rs ? (cs ? w10 : w11) : (cs ? w00 : w01);
        cw[kk][3] = rs ? (cs ? w11 : w10) : (cs ? w01 : w00);
        yci[kk] = yc;
        xci[kk] = xc;
        myrmin = min(myrmin, yc);
        myrmax = max(myrmax, yc);
    }
    atomicMin(&s_rmin, myrmin);
    atomicMax(&s_rmax, myrmax);
    __syncthreads();
    const int w0   = s_rmin;
    const int w1   = min(s_rmax, w0 + MAXR - 1);  // staged pair-rows [w0,w1]
    const int nch  = (w1 - w0 + 1) * CPR;         // 16B staging chunks

    int lofs[9], gfb[9];
    bool outw[9];
#pragma unroll
    for (int kk = 0; kk < 9; ++kk) {
        outw[kk] = yci[kk] > w1;                       // window overflow (rare)
        lofs[kk] = (min(yci[kk], w1) - w0) * W_ + xci[kk];
        gfb[kk]  = yci[kk] * W_ + xci[kk];             // global fallback offset
    }

    const int pix  = h * W_ + wcol;
    const int pr0  = tid / CPR;            // this thread's first staging chunk
    const int q2   = (tid - pr0 * CPR) * 2;

#pragma unroll 1
    for (int c = c0; c < c0 + CPB; ++c) {
        const float* xp = x + (size_t)(b * C_ + c) * HW_;
        const float* xw = xp + w0 * W_;

        // Prefetch this thread's first chunk BEFORE the barrier: global
        // latency overlaps the previous channel's gather phase.
        float2 ra, rb;
        if (tid < nch) {
            __builtin_memcpy(&ra, xw + pr0 * W_ + q2, sizeof(float2));
            __builtin_memcpy(&rb, xw + (pr0 + 1) * W_ + q2, sizeof(float2));
        }

        __syncthreads();   // previous gather done; safe to overwrite LDS
        if (tid < nch) {
            float4 v = make_float4(ra.x, rb.x, ra.y, rb.y);
            *(float4*)&lp[pr0 * W_ + q2] = v;
        }
        for (int k = tid + NT; k < nch; k += NT) {     // typical: 1 extra iter
            const int pr = k / CPR;
            const int q  = (k - pr * CPR) * 2;
            float2 a, bb;
            __builtin_memcpy(&a,  xw + pr * W_ + q, sizeof(float2));
            __builtin_memcpy(&bb, xw + (pr + 1) * W_ + q, sizeof(float2));
            float4 v = make_float4(a.x, bb.x, a.y, bb.y);
            *(float4*)&lp[pr * W_ + q] = v;
        }
        __syncthreads();

        float acc = 0.f;
#pragma unroll
        for (int kk = 0; kk < 9; ++kk) {
            const float2 p0 = lp[lofs[kk]];      // {a0, b0}
            const float2 p1 = lp[lofs[kk] + 1];  // {a1, b1}
            float s = cw[kk][0] * p0.x;
            s = fmaf(cw[kk][2], p0.y, s);
            s = fmaf(cw[kk][1], p1.x, s);
            s = fmaf(cw[kk][3], p1.y, s);
            if (outw[kk]) {                      // execz-skipped when no lane out
                const float* g = xp + gfb[kk];
                float s2 = cw[kk][0] * g[0];
                s2 = fmaf(cw[kk][1], g[1], s2);
                s2 = fmaf(cw[kk][2], g[W_], s2);
                s2 = fmaf(cw[kk][3], g[W_ + 1], s2);
                s = s2;
            }
            acc = fmaf(wgt[c * 9 + kk], s, acc);
        }
        out[(size_t)(b * C_ + c) * HW_ + pix] = acc + bias[c];
    }
}

extern "C" void kernel_launch(void* const* d_in, const int* in_sizes, int n_in,
                              void* d_out, int out_size, void* d_ws, size_t ws_size,
                              hipStream_t stream) {
    const float* x    = (const float*)d_in[0];
    const float* off  = (const float*)d_in[1];
    const float* w    = (const float*)d_in[2];
    const float* bias = (const float*)d_in[3];
    float* out        = (float*)d_out;
    dim3 grid(H_ / TH, B_, CSPLIT);
    deform_dw_conv<<<grid, NT, 0, stream>>>(x, off, w, bias, out);
}

// Round 5
// 257.485 us; speedup vs baseline: 1.3755x; 1.3755x over previous
//
#include <hip/hip_runtime.h>

// Deformable depthwise 3x3 conv, B=8 C=256 H=W=96, fp32.
// R3: LDS gather, stride 100 -> bank=(4*yc+xc)%32 mixed row jitter into banks:
//     38.7M conflict cycles (~35% of kernel). 179 us.
// R4: float2 row-pair layout -> bank PAIRS (2xc)%32, conflicts persisted and
//     staging volume doubled. 260 us. REVERTED.
// R5: R3 structure, LSTR=96. Row stride = 96 dwords = 0 mod 32 -> bank = xc%32,
//     row-jitter-invariant; 64 lanes with near-consecutive xc -> 2/bank (free).
//     Bonus: 96-row capacity = whole plane fits LDS -> window can never
//     overflow (rows staged <= rmax+1 <= 95), no fallback needed.

constexpr int B_ = 8, C_ = 256, H_ = 96, W_ = 96;
constexpr int HW_ = H_ * W_;
constexpr int TH = 4;              // pixel rows per block
constexpr int NT = TH * W_;        // 384 threads = 6 waves
constexpr int CSPLIT = 8;
constexpr int CPB = C_ / CSPLIT;   // 32 channels per block
constexpr int LSTR = 96;           // LDS row stride (dwords) == 0 mod 32:
                                   // bank = xc%32, independent of row jitter
constexpr int LDS_ELEMS = 96 * LSTR;  // full plane worst case: 36864 B

__global__ __launch_bounds__(NT) void deform_dw_conv(
    const float* __restrict__ x, const float* __restrict__ off,
    const float* __restrict__ wgt, const float* __restrict__ bias,
    float* __restrict__ out)
{
    __shared__ float lx[LDS_ELEMS];
    __shared__ int s_rmin, s_rmax;

    const int tid  = threadIdx.x;
    const int r    = tid / W_;
    const int wcol = tid - r * W_;
    const int h    = blockIdx.x * TH + r;
    const int b    = blockIdx.y;
    const int c0   = blockIdx.z * CPB;

    if (tid == 0) { s_rmin = H_; s_rmax = -1; }
    __syncthreads();

    const float* offp = off + (size_t)b * 18 * HW_ + (size_t)h * W_ + wcol;

    // Per-(pixel,tap) params: 4 weights pre-permuted onto loaded positions
    // [0]=(yc,xc) [1]=(yc,xc+1) [2]=(yc+1,xc) [3]=(yc+1,xc+1); validity folded
    // into weights so invalid corners multiply by 0.
    float cw[9][4];
    int lofs[9];
    int myrmin = H_, myrmax = -1;

#pragma unroll
    for (int kk = 0; kk < 9; ++kk) {
        const int i = kk / 3, j = kk % 3;
        const float py = (float)(h - 1 + i) + offp[(2 * kk) * HW_];
        const float px = (float)(wcol - 1 + j) + offp[(2 * kk + 1) * HW_];
        const float fy = floorf(py), fx = floorf(px);
        const float wy = py - fy, wx = px - fx;
        const int y0 = (int)fy, x0 = (int)fx;
        const bool vy0 = (unsigned)y0 < (unsigned)H_;
        const bool vy1 = (unsigned)(y0 + 1) < (unsigned)H_;
        const bool vx0 = (unsigned)x0 < (unsigned)W_;
        const bool vx1 = (unsigned)(x0 + 1) < (unsigned)W_;
        const float w00 = (vy0 && vx0) ? (1.f - wy) * (1.f - wx) : 0.f;
        const float w01 = (vy0 && vx1) ? (1.f - wy) * wx : 0.f;
        const float w10 = (vy1 && vx0) ? wy * (1.f - wx) : 0.f;
        const float w11 = (vy1 && vx1) ? wy * wx : 0.f;
        const int yc = min(max(y0, 0), H_ - 2);
        const int xc = min(max(x0, 0), W_ - 2);
        const bool rs = (y0 == yc);
        const bool cs = (x0 == xc);
        cw[kk][0] = rs ? (cs ? w00 : w01) : (cs ? w10 : w11);
        cw[kk][1] = rs ? (cs ? w01 : w00) : (cs ? w11 : w10);
        cw[kk][2] = rs ? (cs ? w10 : w11) : (cs ? w00 : w01);
        cw[kk][3] = rs ? (cs ? w11 : w10) : (cs ? w01 : w00);
        lofs[kk] = yc * LSTR + xc;
        myrmin = min(myrmin, yc);
        myrmax = max(myrmax, yc);
    }
    atomicMin(&s_rmin, myrmin);
    atomicMax(&s_rmax, myrmax);
    __syncthreads();
    const int rmin  = s_rmin;
    const int nrows = s_rmax + 2 - rmin;   // rows [rmin, rmax+1], <= 96 always
    const int n4    = nrows * (W_ / 4);    // float4 staging chunks
#pragma unroll
    for (int kk = 0; kk < 9; ++kk) lofs[kk] -= rmin * LSTR;

    const int pix   = h * W_ + wcol;
    const int myrow = tid / (W_ / 4);      // staging dest for chunk = tid
    const int mycol = (tid - myrow * (W_ / 4)) * 4;

#pragma unroll 1
    for (int c = c0; c < c0 + CPB; ++c) {
        const float* xp = x + (size_t)(b * C_ + c) * HW_ + rmin * W_;

        // Prefetch this channel's window BEFORE the barrier: global latency
        // overlaps the previous channel's gather phase.
        float4 pf;
        if (tid < n4) __builtin_memcpy(&pf, xp + 4 * tid, sizeof(float4));

        __syncthreads();   // previous gather done; safe to overwrite LDS
        if (tid < n4)
            *(float4*)&lx[myrow * LSTR + mycol] = pf;
        for (int e4 = tid + NT; e4 < n4; e4 += NT) {   // rare: nrows > 16
            const int row = e4 / (W_ / 4);
            const int col = (e4 - row * (W_ / 4)) * 4;
            float4 v;
            __builtin_memcpy(&v, xp + 4 * e4, sizeof(float4));
            *(float4*)&lx[row * LSTR + col] = v;
        }
        __syncthreads();

        float acc = 0.f;
#pragma unroll
        for (int kk = 0; kk < 9; ++kk) {
            const float a0 = lx[lofs[kk]];
            const float a1 = lx[lofs[kk] + 1];
            const float b0 = lx[lofs[kk] + LSTR];
            const float b1 = lx[lofs[kk] + LSTR + 1];
            float s = cw[kk][0] * a0;
            s = fmaf(cw[kk][1], a1, s);
            s = fmaf(cw[kk][2], b0, s);
            s = fmaf(cw[kk][3], b1, s);
            acc = fmaf(wgt[c * 9 + kk], s, acc);
        }
        out[(size_t)(b * C_ + c) * HW_ + pix] = acc + bias[c];
    }
}

extern "C" void kernel_launch(void* const* d_in, const int* in_sizes, int n_in,
                              void* d_out, int out_size, void* d_ws, size_t ws_size,
                              hipStream_t stream) {
    const float* x    = (const float*)d_in[0];
    const float* off  = (const float*)d_in[1];
    const float* w    = (const float*)d_in[2];
    const float* bias = (const float*)d_in[3];
    float* out        = (float*)d_out;
    dim3 grid(H_ / TH, B_, CSPLIT);
    deform_dw_conv<<<grid, NT, 0, stream>>>(x, off, w, bias, out);
}